// Round 5
// baseline (586.889 us; speedup 1.0000x reference)
//
#include <hip/hip_runtime.h>
#include <hip/hip_bf16.h>

// Problem dims (fixed): B=64, Te=1024, De=Dd=H=1024.
#define B_  64
#define TE  1024
#define K_  1024
#define HH  1024
#define MM  (B_ * TE)

typedef __bf16 bf16x8 __attribute__((ext_vector_type(8)));
typedef __bf16 bf16x4 __attribute__((ext_vector_type(4)));
typedef float  f32x4  __attribute__((ext_vector_type(4)));

__device__ __forceinline__ float fast_tanh(float x) {
    // tanh(x) = sign(x) * (1 - e^{-2|x|}) / (1 + e^{-2|x|}); branch-free, no overflow.
    float ax = __builtin_fabsf(x);
    float t  = __expf(-2.0f * ax);
    float r  = (1.0f - t) * __builtin_amdgcn_rcpf(1.0f + t);
    return __builtin_copysignf(r, x);
}

// ---------------------------------------------------------------- prep: cvt(Ua_w) + Wa GEMV, merged
__global__ __launch_bounds__(256) void prep_kernel(const float* __restrict__ Ua_w,
                                                   __bf16* __restrict__ uawB,
                                                   const float* __restrict__ dec,
                                                   const float* __restrict__ Wa_w,
                                                   const float* __restrict__ Wa_b,
                                                   float* __restrict__ WaOut) {
    int bid = blockIdx.x, tid = threadIdx.x;
    if (bid < 256) {
        const long n4 = (long)HH * 1024 / 4;
        const float4* in4 = (const float4*)Ua_w;
        bf16x4* out4 = (bf16x4*)uawB;
        for (long j = bid * 256 + tid; j < n4; j += 65536) {
            float4 v = in4[j];
            bf16x4 o;
            o[0] = (__bf16)v.x; o[1] = (__bf16)v.y; o[2] = (__bf16)v.z; o[3] = (__bf16)v.w;
            out4[j] = o;
        }
        return;
    }
    int wb = bid - 256;
    int b = wb >> 4, hc = wb & 15;
    int wave = tid >> 6, lane = tid & 63;

    const float4* d4 = (const float4*)(dec + b * 1024);
    float4 dreg[4];
    #pragma unroll
    for (int j = 0; j < 4; j++) dreg[j] = d4[lane * 4 + j];

    #pragma unroll 4
    for (int i = 0; i < 16; i++) {
        int h = hc * 64 + wave * 16 + i;
        const float4* wr = (const float4*)(Wa_w + (long)h * 1024);
        float a = 0.0f;
        #pragma unroll
        for (int j = 0; j < 4; j++) {
            float4 v = wr[lane * 4 + j];
            a += v.x * dreg[j].x + v.y * dreg[j].y + v.z * dreg[j].z + v.w * dreg[j].w;
        }
        #pragma unroll
        for (int off = 32; off > 0; off >>= 1)
            a += __shfl_xor(a, off, 64);
        if (lane == 0) WaOut[b * 1024 + h] = a + Wa_b[h];
    }
}

// ---------------------------------------------------------------- fused score GEMM
// scores[m] += sum_h Va_w[h]*tanh(enc[m,:]·Ua_w[h,:] + Wa[b,h] + Ua_b[h])
// BM=128 x BN=256, KT=64, 512 threads (8 waves, wave tile 64x64, acc[4][4]).
// 3-deep B ring (gload_lds; tile staged at iter t lands by end of t+1 = 2 iters
// of slack > HBM latency) + 2-deep A dbuf (reg-load fp32 -> cvt -> ds_write one
// tile ahead). ONE barrier per K-tile; counted vmcnt(8) keeps A(t+2)+B(t+2) in
// flight across it; never drains to 0 mid-loop. 1 block/CU (133 KB dynamic LDS).
// Proven 8-slot XOR swizzle both operands (0 conflicts in R0/R3).
#define MT 128
#define NP 256
#define KT 64
#define NKT (K_ / KT)
#define SMEM_SCORE (2 * MT * KT * 2 + 3 * NP * KT * 2 + 2 * NP * 4)

__global__ __launch_bounds__(512, 2) void score_gemm(
    const float* __restrict__ Af,    // [MM][1024] enc fp32
    __bf16* __restrict__ encB,       // [MM][1024] bf16 out (written by y==0 blocks)
    const __bf16* __restrict__ Bm,   // [1024][1024] Ua_w bf16
    const float* __restrict__ Wa,    // [64][1024]
    const float* __restrict__ Ua_b,  // [1024]
    const float* __restrict__ Va_w,  // [1024]
    float* __restrict__ scores)      // [MM], pre-zeroed, atomic accumulate
{
    extern __shared__ char smem[];
    __bf16* aBuf0 = (__bf16*)smem;                       // 2 x 16 KB
    __bf16* aBuf1 = aBuf0 + MT * KT;
    __bf16* bBuf0 = (__bf16*)(smem + 2 * MT * KT * 2);   // 3 x 32 KB
    __bf16* bBuf1 = bBuf0 + NP * KT;
    __bf16* bBuf2 = bBuf1 + NP * KT;
    float*  sVa   = (float*)(smem + 2 * MT * KT * 2 + 3 * NP * KT * 2);
    float*  sWU   = sVa + NP;

    const int tid  = threadIdx.x;
    const int wave = tid >> 6;
    const int lane = tid & 63;
    const int quad = lane >> 4;
    const int l16  = lane & 15;
    const int wr   = wave >> 2;      // 0..1 -> 64-row half
    const int wc   = wave & 3;       // 0..3 -> 64-col quarter

    // bid -> (x strip, y quarter); groups of 32 bids = 8 XCD slots x 4 y sharing x.
    const int bid = blockIdx.x;
    const int grp = bid >> 5;
    const int r5  = bid & 31;
    const int y   = r5 >> 3;
    const int x   = grp * 8 + (r5 & 7);

    const int rowBase = x * MT;
    const int colBase = y * NP;
    const int b       = rowBase >> 10;
    const bool wb     = (y == 0);    // this block writes the bf16 A strip

    if (tid < NP) {
        int h = colBase + tid;
        sVa[tid] = Va_w[h];
        sWU[tid] = Wa[b * 1024 + h] + Ua_b[h];
    }

    const long aBase = (long)rowBase * K_;
    const long bBase = (long)colBase * K_;

    // A chunks (8 bf16 each): c = i*512+tid; r=c>>3 (0..127); seg=(c&7)^(r&7). i=0..1
    int rrA[2], sgA[2];
    #pragma unroll
    for (int i = 0; i < 2; i++) {
        int c = i * 512 + tid;
        rrA[i] = c >> 3;
        sgA[i] = (c & 7) ^ (rrA[i] & 7);
    }

    float4 pre[2][2];

    auto loadA = [&](int tk) {       // 4 float4 global loads -> pre
        int k = tk * KT;
        #pragma unroll
        for (int i = 0; i < 2; i++) {
            const float4* p = (const float4*)(Af + aBase + (long)rrA[i] * K_ + k + sgA[i] * 8);
            pre[i][0] = p[0]; pre[i][1] = p[1];
        }
    };
    auto cvtA = [&](__bf16* dst, int tk) {   // pre -> bf16 -> LDS (+2 encB stores if wb)
        int k = tk * KT;
        #pragma unroll
        for (int i = 0; i < 2; i++) {
            bf16x8 v;
            v[0] = (__bf16)pre[i][0].x; v[1] = (__bf16)pre[i][0].y;
            v[2] = (__bf16)pre[i][0].z; v[3] = (__bf16)pre[i][0].w;
            v[4] = (__bf16)pre[i][1].x; v[5] = (__bf16)pre[i][1].y;
            v[6] = (__bf16)pre[i][1].z; v[7] = (__bf16)pre[i][1].w;
            *(bf16x8*)(dst + (i * 512 + tid) * 8) = v;
            if (wb)
                *(bf16x8*)(encB + aBase + (long)rrA[i] * K_ + k + sgA[i] * 8) = v;
        }
    };
    auto stageB = [&](__bf16* dst, int tk) { // 4 gload_lds (linear dest, swizzled src)
        int k = tk * KT;
        #pragma unroll
        for (int i = 0; i < 4; i++) {
            int c = i * 512 + tid;
            int r = c >> 3;
            int seg = (c & 7) ^ (r & 7);
            __builtin_amdgcn_global_load_lds(
                (const __attribute__((address_space(1))) unsigned int*)(Bm + bBase + (long)r * K_ + k + seg * 8),
                (__attribute__((address_space(3))) unsigned int*)(dst + c * 8), 16, 0, 0);
        }
    };

    f32x4 acc[4][4] = {};
    bf16x8 afr[4][2], bfr[4][2];

    auto readFrags = [&](const __bf16* pa, const __bf16* pb) {
        #pragma unroll
        for (int s = 0; s < 4; s++) {
            int r = wr * 64 + s * 16 + l16;
            #pragma unroll
            for (int ks = 0; ks < 2; ks++) {
                int slot = (ks * 4 + quad) ^ (r & 7);
                afr[s][ks] = *(const bf16x8*)(pa + r * KT + slot * 8);
            }
        }
        #pragma unroll
        for (int t = 0; t < 4; t++) {
            int r = wc * 64 + t * 16 + l16;
            #pragma unroll
            for (int ks = 0; ks < 2; ks++) {
                int slot = (ks * 4 + quad) ^ (r & 7);
                bfr[t][ks] = *(const bf16x8*)(pb + r * KT + slot * 8);
            }
        }
    };
    auto mfmaAll = [&]() {
        __builtin_amdgcn_s_setprio(1);
        #pragma unroll
        for (int ks = 0; ks < 2; ks++)
            #pragma unroll
            for (int s = 0; s < 4; s++)
                #pragma unroll
                for (int t = 0; t < 4; t++)
                    acc[s][t] = __builtin_amdgcn_mfma_f32_16x16x32_bf16(afr[s][ks], bfr[t][ks], acc[s][t], 0, 0, 0);
        __builtin_amdgcn_s_setprio(0);
    };

    __bf16 *aCur = aBuf0, *aNxt = aBuf1;
    __bf16 *bCur = bBuf0, *bNxt = bBuf1, *bStage = bBuf2;

    // ---- prologue: A0 in LDS, B0+B1 staged, A1 in regs ------------
    loadA(0);                        // 4 loads
    cvtA(aCur, 0);                   // auto-waits A0; ds_writes (+stores)
    stageB(bCur, 0);                 // 4
    loadA(1);                        // 4
    stageB(bNxt, 1);                 // 4
    // drain B0 (+stores); keep A1+B1 (8 newest) in flight
    asm volatile("s_waitcnt vmcnt(8) lgkmcnt(0)" ::: "memory");
    __builtin_amdgcn_sched_barrier(0);
    __builtin_amdgcn_s_barrier();
    asm volatile("" ::: "memory");

    // ---- main loop: one counted barrier per K-tile ----------------
    // Invariant at iter kt entry: aCur/bCur = tile kt ready; pre = A(kt+1);
    // B(kt+1) in flight (lands by this iter's vmcnt(8)).
    for (int kt = 0; kt < NKT - 2; ++kt) {
        cvtA(aNxt, kt + 1);          // auto vmcnt(4): waits A(kt+1), keeps B(kt+1)
        loadA(kt + 2);               // 4 loads
        stageB(bStage, kt + 2);      // 4 gload_lds into slot freed at iter kt-1
        readFrags(aCur, bCur);       // 16 ds_read_b128, conflict-free
        // drain B(kt+1) (+stores); keep A(kt+2)+B(kt+2):
        asm volatile("s_waitcnt vmcnt(8) lgkmcnt(0)" ::: "memory");
        __builtin_amdgcn_sched_barrier(0);
        __builtin_amdgcn_s_barrier();
        asm volatile("" ::: "memory");
        mfmaAll();                   // loads for kt+2 fly underneath
        __bf16* ta = aCur; aCur = aNxt; aNxt = ta;
        __bf16* tb = bCur; bCur = bNxt; bNxt = bStage; bStage = tb;
    }
    // ---- kt = NKT-2: last staging already done --------------------
    {
        cvtA(aNxt, NKT - 1);
        readFrags(aCur, bCur);
        asm volatile("s_waitcnt vmcnt(0) lgkmcnt(0)" ::: "memory");
        __builtin_amdgcn_sched_barrier(0);
        __builtin_amdgcn_s_barrier();
        asm volatile("" ::: "memory");
        mfmaAll();
        __bf16* ta = aCur; aCur = aNxt; aNxt = ta;
        __bf16* tb = bCur; bCur = bNxt; bNxt = bStage; bStage = tb;
    }
    // ---- kt = NKT-1 ----------------------------------------------
    readFrags(aCur, bCur);
    mfmaAll();                       // compiler inserts lgkmcnt before MFMA

    // Epilogue. C/D layout: row = quad*4 + reg, col = l16.
    float rs[4][4] = {};
    #pragma unroll
    for (int s = 0; s < 4; s++)
        #pragma unroll
        for (int t = 0; t < 4; t++) {
            int hl = wc * 64 + t * 16 + l16;
            float va = sVa[hl], wu = sWU[hl];
            #pragma unroll
            for (int r = 0; r < 4; r++)
                rs[s][r] += va * fast_tanh(acc[s][t][r] + wu);
        }

    #pragma unroll
    for (int s = 0; s < 4; s++)
        #pragma unroll
        for (int r = 0; r < 4; r++) {
            float v = rs[s][r];
            v += __shfl_xor(v, 1, 64);
            v += __shfl_xor(v, 2, 64);
            v += __shfl_xor(v, 4, 64);
            v += __shfl_xor(v, 8, 64);
            if (l16 == 0)
                atomicAdd(&scores[rowBase + wr * 64 + s * 16 + quad * 4 + r], v);
        }
}

// ---------------------------------------------------------------- softmax over Te, in place
__global__ __launch_bounds__(256) void softmax_kernel(float* __restrict__ s) {
    __shared__ float red[8];
    int b = blockIdx.x, tid = threadIdx.x;
    int wave = tid >> 6, lane = tid & 63;
    float4* row = (float4*)(s + b * 1024);
    float4 v = row[tid];
    float m = fmaxf(fmaxf(v.x, v.y), fmaxf(v.z, v.w));
    #pragma unroll
    for (int off = 32; off > 0; off >>= 1)
        m = fmaxf(m, __shfl_xor(m, off, 64));
    if (lane == 0) red[wave] = m;
    __syncthreads();
    m = fmaxf(fmaxf(red[0], red[1]), fmaxf(red[2], red[3]));
    v.x = expf(v.x - m); v.y = expf(v.y - m); v.z = expf(v.z - m); v.w = expf(v.w - m);
    float sum = v.x + v.y + v.z + v.w;
    #pragma unroll
    for (int off = 32; off > 0; off >>= 1)
        sum += __shfl_xor(sum, off, 64);
    if (lane == 0) red[4 + wave] = sum;
    __syncthreads();
    float inv = 1.0f / (red[4] + red[5] + red[6] + red[7]);
    v.x *= inv; v.y *= inv; v.z *= inv; v.w *= inv;
    row[tid] = v;
}

// ---------------------------------------------------------------- context partials (atomic-free)
__global__ __launch_bounds__(256) void context_partial(const __bf16* __restrict__ enc,
                                                       const float* __restrict__ w,
                                                       float* __restrict__ pb) {
    __shared__ float red[2][128][8];     // 8 KB
    int b = blockIdx.x, ec = blockIdx.y, tid = threadIdx.x;
    int eo = tid >> 7;
    int dc = tid & 127;
    const bf16x8* enc8 = (const bf16x8*)(enc + ((long)b * 1024 + ec * 128) * 1024);
    const float* wrow = w + b * 1024 + ec * 128;
    float acc[8] = {};
    #pragma unroll 4
    for (int e = eo; e < 128; e += 2) {
        float we = wrow[e];
        bf16x8 v = enc8[e * 128 + dc];
        #pragma unroll
        for (int j = 0; j < 8; j++) acc[j] += we * (float)v[j];
    }
    #pragma unroll
    for (int j = 0; j < 8; j++) red[eo][dc][j] = acc[j];
    __syncthreads();
    if (eo == 0) {
        float* o = pb + ((long)(b * 8 + ec)) * 1024 + dc * 8;
        #pragma unroll
        for (int j = 0; j < 8; j++) o[j] = red[0][dc][j] + red[1][dc][j];
    }
}

__global__ void context_reduce(const float* __restrict__ pb, float* __restrict__ out) {
    int b = blockIdx.x, tid = threadIdx.x;
    const f32x4* p4 = (const f32x4*)pb;
    f32x4 s = {0.f, 0.f, 0.f, 0.f};
    #pragma unroll
    for (int ec = 0; ec < 8; ec++)
        s += p4[(b * 8 + ec) * 256 + tid];
    ((f32x4*)out)[b * 256 + tid] = s;
}

// ----------------------------------------------------------------
extern "C" void kernel_launch(void* const* d_in, const int* in_sizes, int n_in,
                              void* d_out, int out_size, void* d_ws, size_t ws_size,
                              hipStream_t stream) {
    (void)in_sizes; (void)n_in; (void)ws_size;
    const float* enc   = (const float*)d_in[0];
    const float* dec   = (const float*)d_in[1];
    const float* Wa_w  = (const float*)d_in[2];
    const float* Wa_b  = (const float*)d_in[3];
    const float* Ua_w  = (const float*)d_in[4];
    const float* Ua_b  = (const float*)d_in[5];
    const float* Va_w  = (const float*)d_in[6];
    // d_in[7] = Va_b: softmax-invariant -> dropped.
    float* out = (float*)d_out;

    char* w = (char*)d_ws;
    __bf16* encB = (__bf16*)w;  w += (size_t)MM * 1024 * 2;
    __bf16* uawB = (__bf16*)w;  w += (size_t)HH * 1024 * 2;
    float* WaBuf = (float*)w;   w += (size_t)B_ * HH * 4;
    float* scores = (float*)w;  w += (size_t)MM * 4;
    float* pb = (float*)w;      w += (size_t)B_ * 8 * 1024 * 4;

    static bool smemSet = false;
    if (!smemSet) {
        hipFuncSetAttribute((const void*)score_gemm,
                            hipFuncAttributeMaxDynamicSharedMemorySize, SMEM_SCORE);
        smemSet = true;
    }

    hipMemsetAsync(scores, 0, (size_t)MM * 4, stream);
    prep_kernel<<<dim3(256 + B_ * 16), 256, 0, stream>>>(Ua_w, uawB, dec, Wa_w, Wa_b, WaBuf);
    score_gemm<<<dim3((MM / MT) * (HH / NP)), 512, SMEM_SCORE, stream>>>(enc, encB, uawB, WaBuf, Ua_b, Va_w, scores);
    softmax_kernel<<<dim3(B_), 256, 0, stream>>>(scores);
    context_partial<<<dim3(B_, 8), 256, 0, stream>>>(encB, scores, pb);
    context_reduce<<<dim3(B_), 256, 0, stream>>>(pb, out);
}

// Round 6
// 511.162 us; speedup vs baseline: 1.1481x; 1.1481x over previous
//
#include <hip/hip_runtime.h>
#include <hip/hip_bf16.h>

// Problem dims (fixed): B=64, Te=1024, De=Dd=H=1024.
#define B_  64
#define TE  1024
#define K_  1024
#define HH  1024
#define MM  (B_ * TE)

typedef __bf16 bf16x8 __attribute__((ext_vector_type(8)));
typedef __bf16 bf16x4 __attribute__((ext_vector_type(4)));
typedef float  f32x4  __attribute__((ext_vector_type(4)));

__device__ __forceinline__ float fast_tanh(float x) {
    // tanh(x) = sign(x) * (1 - e^{-2|x|}) / (1 + e^{-2|x|}); branch-free, no overflow.
    float ax = __builtin_fabsf(x);
    float t  = __expf(-2.0f * ax);
    float r  = (1.0f - t) * __builtin_amdgcn_rcpf(1.0f + t);
    return __builtin_copysignf(r, x);
}

// ---------------------------------------------------------------- prep: cvt(Ua_w) + Wa GEMV + zero(scores)
// blocks 0..255: fp32->bf16 convert of Ua_w, plus zeroing of scores (replaces memset dispatch).
// blocks 256..1279: Wa[b,h] = dec[b]·Wa_w[h] + Wa_b[h].
__global__ __launch_bounds__(256) void prep_kernel(const float* __restrict__ Ua_w,
                                                   __bf16* __restrict__ uawB,
                                                   const float* __restrict__ dec,
                                                   const float* __restrict__ Wa_w,
                                                   const float* __restrict__ Wa_b,
                                                   float* __restrict__ WaOut,
                                                   float* __restrict__ scores) {
    int bid = blockIdx.x, tid = threadIdx.x;
    if (bid < 256) {
        long zi = (long)bid * 256 + tid;             // scores: 65536 floats = 16384 float4
        if (zi < MM / 4) ((f32x4*)scores)[zi] = f32x4{0.f, 0.f, 0.f, 0.f};
        const long n4 = (long)HH * 1024 / 4;
        const float4* in4 = (const float4*)Ua_w;
        bf16x4* out4 = (bf16x4*)uawB;
        for (long j = bid * 256 + tid; j < n4; j += 65536) {
            float4 v = in4[j];
            bf16x4 o;
            o[0] = (__bf16)v.x; o[1] = (__bf16)v.y; o[2] = (__bf16)v.z; o[3] = (__bf16)v.w;
            out4[j] = o;
        }
        return;
    }
    int wb = bid - 256;
    int b = wb >> 4, hc = wb & 15;
    int wave = tid >> 6, lane = tid & 63;

    const float4* d4 = (const float4*)(dec + b * 1024);
    float4 dreg[4];
    #pragma unroll
    for (int j = 0; j < 4; j++) dreg[j] = d4[lane * 4 + j];

    #pragma unroll 4
    for (int i = 0; i < 16; i++) {
        int h = hc * 64 + wave * 16 + i;
        const float4* wr = (const float4*)(Wa_w + (long)h * 1024);
        float a = 0.0f;
        #pragma unroll
        for (int j = 0; j < 4; j++) {
            float4 v = wr[lane * 4 + j];
            a += v.x * dreg[j].x + v.y * dreg[j].y + v.z * dreg[j].z + v.w * dreg[j].w;
        }
        #pragma unroll
        for (int off = 32; off > 0; off >>= 1)
            a += __shfl_xor(a, off, 64);
        if (lane == 0) WaOut[b * 1024 + h] = a + Wa_b[h];
    }
}

// ---------------------------------------------------------------- fused score GEMM
// scores[m] += sum_h Va_w[h]*tanh(enc[m,:]·Ua_w[h,:] + Wa[b,h] + Ua_b[h])
// ROUND-0 VERBATIM (the proven 654-TF / 210-µs config; 4 restructures all lost):
// 128x256 tile, KT=64 single-buffer, 2 barriers/K-step, 8-slot XOR swizzle,
// (256,2). y==0 blocks also emit the bf16 A tile to encB.
#define MT 128
#define NP 256
#define KT 64

__global__ __launch_bounds__(256, 2) void score_gemm(
    const float* __restrict__ Af,    // [MM][1024] enc fp32
    __bf16* __restrict__ encB,       // [MM][1024] bf16 out (written by y==0 blocks)
    const __bf16* __restrict__ Bm,   // [1024][1024] Ua_w bf16
    const float* __restrict__ Wa,    // [64][1024]
    const float* __restrict__ Ua_b,  // [1024]
    const float* __restrict__ Va_w,  // [1024]
    float* __restrict__ scores)      // [MM], pre-zeroed, atomic accumulate
{
    __shared__ __bf16 sA[MT * KT];   // 16 KB, swizzled: row r, slot s' holds seg s'^(r&7)
    __shared__ __bf16 sB[NP * KT];   // 32 KB
    __shared__ float sVa[NP];
    __shared__ float sWU[NP];

    const int tid  = threadIdx.x;
    const int wave = tid >> 6;
    const int lane = tid & 63;
    const int quad = lane >> 4;
    const int l16  = lane & 15;
    const int wm   = wave >> 1;      // 0..1 -> 64-row half
    const int wn   = wave & 1;       // 0..1 -> 128-col half

    // bid -> (x strip, y quarter); groups of 32 bids = 8 XCD slots x 4 y sharing x.
    const int bid = blockIdx.x;
    const int grp = bid >> 5;
    const int r5  = bid & 31;
    const int y   = r5 >> 3;
    const int x   = grp * 8 + (r5 & 7);

    const int rowBase = x * MT;
    const int colBase = y * NP;
    const int b       = rowBase >> 10;
    const bool wb     = (y == 0);    // this block writes the bf16 A strip

    if (tid < NP) {
        int h = colBase + tid;
        sVa[tid] = Va_w[h];
        sWU[tid] = Wa[b * 1024 + h] + Ua_b[h];
    }

    // My 4 A chunks (8 bf16 each): c = i*256+tid; r=c>>3; seg=(c&7)^(r&7)
    int rr[4], sg[4];
    #pragma unroll
    for (int i = 0; i < 4; i++) {
        int c = i * 256 + tid;
        rr[i] = c >> 3;
        sg[i] = (c & 7) ^ (rr[i] & 7);
    }

    f32x4 acc[4][8] = {};            // [m-subtile s][n-subtile t]

    const long aBase = (long)rowBase * K_;
    const long bBase = (long)colBase * K_;

    float4 pre[4][2];
    #pragma unroll
    for (int i = 0; i < 4; i++) {    // prefetch A(k0=0)
        const float4* p = (const float4*)(Af + aBase + (long)rr[i] * K_ + sg[i] * 8);
        pre[i][0] = p[0]; pre[i][1] = p[1];
    }

    for (int k0 = 0; k0 < K_; k0 += KT) {
        __syncthreads();             // prior ds_reads done; prefetch loads drained here
        #pragma unroll
        for (int i = 0; i < 4; i++) {            // A: cvt + ds_write (+ optional writeback)
            bf16x8 v;
            v[0] = (__bf16)pre[i][0].x; v[1] = (__bf16)pre[i][0].y;
            v[2] = (__bf16)pre[i][0].z; v[3] = (__bf16)pre[i][0].w;
            v[4] = (__bf16)pre[i][1].x; v[5] = (__bf16)pre[i][1].y;
            v[6] = (__bf16)pre[i][1].z; v[7] = (__bf16)pre[i][1].w;
            *(bf16x8*)(sA + (i * 256 + tid) * 8) = v;
            if (wb)
                *(bf16x8*)(encB + aBase + (long)rr[i] * K_ + k0 + sg[i] * 8) = v;
        }
        #pragma unroll
        for (int i = 0; i < 8; i++) {            // B: 256x64 = 2048 chunks via async LDS
            int c = i * 256 + tid;
            int r = c >> 3, slot = c & 7;
            int seg = slot ^ (r & 7);
            __builtin_amdgcn_global_load_lds(
                (const __attribute__((address_space(1))) unsigned int*)(Bm + bBase + (long)r * K_ + k0 + seg * 8),
                (__attribute__((address_space(3))) unsigned int*)(sB + c * 8), 16, 0, 0);
        }
        __syncthreads();             // staged data visible

        if (k0 + KT < K_) {          // issue next A prefetch; hides under MFMA phase
            #pragma unroll
            for (int i = 0; i < 4; i++) {
                const float4* p = (const float4*)(Af + aBase + (long)rr[i] * K_ + (k0 + KT) + sg[i] * 8);
                pre[i][0] = p[0]; pre[i][1] = p[1];
            }
        }

        #pragma unroll
        for (int ks = 0; ks < 2; ks++) {
            bf16x8 bfr[8];
            #pragma unroll
            for (int t = 0; t < 8; t++) {
                int r = wn * 128 + t * 16 + l16;
                int slot = (ks * 4 + quad) ^ (r & 7);
                bfr[t] = *(const bf16x8*)(sB + r * KT + slot * 8);
            }
            #pragma unroll
            for (int s = 0; s < 4; s++) {
                int r = wm * 64 + s * 16 + l16;
                int slot = (ks * 4 + quad) ^ (r & 7);
                bf16x8 af = *(const bf16x8*)(sA + r * KT + slot * 8);
                #pragma unroll
                for (int t = 0; t < 8; t++)
                    acc[s][t] = __builtin_amdgcn_mfma_f32_16x16x32_bf16(af, bfr[t], acc[s][t], 0, 0, 0);
            }
        }
    }

    // Epilogue. C/D layout: row = quad*4 + reg, col = l16.
    float rs[4][4] = {};
    #pragma unroll
    for (int s = 0; s < 4; s++)
        #pragma unroll
        for (int t = 0; t < 8; t++) {
            int hl = wn * 128 + t * 16 + l16;
            float va = sVa[hl], wu = sWU[hl];
            #pragma unroll
            for (int r = 0; r < 4; r++)
                rs[s][r] += va * fast_tanh(acc[s][t][r] + wu);
        }

    #pragma unroll
    for (int s = 0; s < 4; s++)
        #pragma unroll
        for (int r = 0; r < 4; r++) {
            float v = rs[s][r];
            v += __shfl_xor(v, 1, 64);
            v += __shfl_xor(v, 2, 64);
            v += __shfl_xor(v, 4, 64);
            v += __shfl_xor(v, 8, 64);
            if (l16 == 0)
                atomicAdd(&scores[rowBase + wm * 64 + s * 16 + quad * 4 + r], v);
        }
}

// ---------------------------------------------------------------- context partials + inline softmax
// Block (b, ec): recompute softmax reduction over the full 1024-row (4 KB read,
// two shuffle reductions -- cheap, removes the 64-block softmax dispatch), keep
// this block's 128 weights in LDS, then weights·enc partial dot -> pb.
__global__ __launch_bounds__(256) void context_partial(const __bf16* __restrict__ enc,
                                                       const float* __restrict__ sc,
                                                       float* __restrict__ pb) {
    __shared__ float red[2][128][8];     // 8 KB
    __shared__ float wLds[128];
    __shared__ float xr[8];
    int b = blockIdx.x, ec = blockIdx.y, tid = threadIdx.x;
    int wave = tid >> 6, lane = tid & 63;

    // ---- softmax over scores[b][:] (redundant per block) ----
    float4 v = ((const float4*)(sc + b * 1024))[tid];
    float m = fmaxf(fmaxf(v.x, v.y), fmaxf(v.z, v.w));
    #pragma unroll
    for (int off = 32; off > 0; off >>= 1)
        m = fmaxf(m, __shfl_xor(m, off, 64));
    if (lane == 0) xr[wave] = m;
    __syncthreads();
    m = fmaxf(fmaxf(xr[0], xr[1]), fmaxf(xr[2], xr[3]));
    float ex = expf(v.x - m), ey = expf(v.y - m), ez = expf(v.z - m), ew = expf(v.w - m);
    float sum = ex + ey + ez + ew;
    #pragma unroll
    for (int off = 32; off > 0; off >>= 1)
        sum += __shfl_xor(sum, off, 64);
    if (lane == 0) xr[4 + wave] = sum;
    __syncthreads();
    float inv = 1.0f / (xr[4] + xr[5] + xr[6] + xr[7]);
    // threads ec*32 .. ec*32+31 hold this block's 128 e-values (e = 4*tid .. 4*tid+3)
    int u = tid - ec * 32;
    if (u >= 0 && u < 32) {
        wLds[u * 4 + 0] = ex * inv;
        wLds[u * 4 + 1] = ey * inv;
        wLds[u * 4 + 2] = ez * inv;
        wLds[u * 4 + 3] = ew * inv;
    }
    __syncthreads();

    // ---- partial dot: e-rows ec*128..+128 ----
    int eo = tid >> 7;
    int dc = tid & 127;
    const bf16x8* enc8 = (const bf16x8*)(enc + ((long)b * 1024 + ec * 128) * 1024);
    float acc[8] = {};
    #pragma unroll 4
    for (int e = eo; e < 128; e += 2) {
        float we = wLds[e];              // same-address broadcast, conflict-free
        bf16x8 vv = enc8[e * 128 + dc];
        #pragma unroll
        for (int j = 0; j < 8; j++) acc[j] += we * (float)vv[j];
    }
    #pragma unroll
    for (int j = 0; j < 8; j++) red[eo][dc][j] = acc[j];
    __syncthreads();
    if (eo == 0) {
        float* o = pb + ((long)(b * 8 + ec)) * 1024 + dc * 8;
        #pragma unroll
        for (int j = 0; j < 8; j++) o[j] = red[0][dc][j] + red[1][dc][j];
    }
}

// out[b][:] = sum_ec pb[b][ec][:]
__global__ void context_reduce(const float* __restrict__ pb, float* __restrict__ out) {
    int b = blockIdx.x, tid = threadIdx.x;
    const f32x4* p4 = (const f32x4*)pb;
    f32x4 s = {0.f, 0.f, 0.f, 0.f};
    #pragma unroll
    for (int ec = 0; ec < 8; ec++)
        s += p4[(b * 8 + ec) * 256 + tid];
    ((f32x4*)out)[b * 256 + tid] = s;
}

// ----------------------------------------------------------------
extern "C" void kernel_launch(void* const* d_in, const int* in_sizes, int n_in,
                              void* d_out, int out_size, void* d_ws, size_t ws_size,
                              hipStream_t stream) {
    (void)in_sizes; (void)n_in; (void)ws_size; (void)out_size;
    const float* enc   = (const float*)d_in[0];
    const float* dec   = (const float*)d_in[1];
    const float* Wa_w  = (const float*)d_in[2];
    const float* Wa_b  = (const float*)d_in[3];
    const float* Ua_w  = (const float*)d_in[4];
    const float* Ua_b  = (const float*)d_in[5];
    const float* Va_w  = (const float*)d_in[6];
    // d_in[7] = Va_b: softmax-invariant -> dropped.
    float* out = (float*)d_out;

    char* w = (char*)d_ws;
    __bf16* encB = (__bf16*)w;  w += (size_t)MM * 1024 * 2;
    __bf16* uawB = (__bf16*)w;  w += (size_t)HH * 1024 * 2;
    float* WaBuf = (float*)w;   w += (size_t)B_ * HH * 4;
    float* scores = (float*)w;  w += (size_t)MM * 4;
    float* pb = (float*)w;      w += (size_t)B_ * 8 * 1024 * 4;

    // 4 dispatches (was 6): memset folded into prep, softmax folded into context.
    prep_kernel<<<dim3(256 + B_ * 16), 256, 0, stream>>>(Ua_w, uawB, dec, Wa_w, Wa_b, WaBuf, scores);
    score_gemm<<<dim3((MM / MT) * (HH / NP)), 256, 0, stream>>>(enc, encB, uawB, WaBuf, Ua_b, Va_w, scores);
    context_partial<<<dim3(B_, 8), 256, 0, stream>>>(encB, scores, pb);
    context_reduce<<<dim3(B_), 256, 0, stream>>>(pb, out);
}